// Round 1
// 269.483 us; speedup vs baseline: 1.0139x; 1.0139x over previous
//
#include <hip/hip_runtime.h>

#define TAILB 12.0f
#define INV2048 4.8828125e-4f

typedef _Float16 half8 __attribute__((ext_vector_type(8)));
typedef _Float16 half4 __attribute__((ext_vector_type(4)));
typedef __fp16 fp16x2 __attribute__((ext_vector_type(2)));   // pkrtz return type
typedef __attribute__((ext_vector_type(4))) float f32x4;

#define MFMAH __builtin_amdgcn_mfma_f32_16x16x32_f16

// In-wave LDS ordering fence: all lanes of the wave run lockstep; this
// replaces __syncthreads for wave-local producer->consumer through LDS.
// sched_barrier pins compiler scheduling (rule: hipcc hoists reg-only ops
// past inline-asm waitcnt otherwise); "memory" clobber fences memory ops.
#define WAVE_SYNC() do {                                  \
    __builtin_amdgcn_sched_barrier(0);                    \
    asm volatile("s_waitcnt lgkmcnt(0)" ::: "memory");    \
    __builtin_amdgcn_sched_barrier(0);                    \
} while (0)

// fast softplus: log(1+e^z); abs err ~2^-24 — r13-verified (absmax 0.5)
__device__ __forceinline__ float softplus_f(float z) {
    return (z > 15.f) ? z : __logf(1.f + __expf(z));
}

// fp16 2-term scaled split (RNE, prep only)
__device__ __forceinline__ void split2h(float v, _Float16& o0, _Float16& o1) {
    _Float16 h0 = (_Float16)v;
    float r1 = v - (float)h0;
    o0 = h0;
    o1 = (_Float16)(r1 * 2048.0f);
}

// pkrtz-based split of 4 values -> two packed half4 planes (RTZ both terms)
__device__ __forceinline__ void split4_pk(const float* v, half4& p0, half4& p1) {
    fp16x2 lo = __builtin_amdgcn_cvt_pkrtz(v[0], v[1]);
    fp16x2 hi = __builtin_amdgcn_cvt_pkrtz(v[2], v[3]);
    float r0 = (v[0] - (float)lo.x) * 2048.f;
    float r1 = (v[1] - (float)lo.y) * 2048.f;
    float r2 = (v[2] - (float)hi.x) * 2048.f;
    float r3 = (v[3] - (float)hi.y) * 2048.f;
    fp16x2 rlo = __builtin_amdgcn_cvt_pkrtz(r0, r1);
    fp16x2 rhi = __builtin_amdgcn_cvt_pkrtz(r2, r3);
    p0 = (half4){(_Float16)lo.x, (_Float16)lo.y, (_Float16)hi.x, (_Float16)hi.y};
    p1 = (half4){(_Float16)rlo.x, (_Float16)rlo.y, (_Float16)rhi.x, (_Float16)rhi.y};
}

// ---------------- prep: identical layout to v10..v14 ----------------
__global__ __launch_bounds__(256)
void prep_v15(const float* __restrict__ W1, const float* __restrict__ b1,
              const float* __restrict__ W2, const float* __restrict__ W3,
              _Float16* __restrict__ W2F, _Float16* __restrict__ W3F,
              float4* __restrict__ w1p)
{
    int id = blockIdx.x * 256 + threadIdx.x;
    if (id < 65536) {
        int j = id & 7, ln = (id >> 3) & 63, tile = id >> 9;
        int cs = tile & 3, t = (tile >> 2) & 1, wv = (tile >> 3) & 3, l = tile >> 5;
        int n = 32 * wv + 16 * t + (ln & 15);
        int k = 32 * cs + 8 * (ln >> 4) + j;
        _Float16 a, b;
        split2h(W2[l * 16384 + n * 128 + k], a, b);
        W2F[(tile * 2 + 0) * 512 + ln * 8 + j] = a;
        W2F[(tile * 2 + 1) * 512 + ln * 8 + j] = b;
    } else if (id < 90112) {
        int t2 = id - 65536;
        int j = t2 & 7, ln = (t2 >> 3) & 63, tile3 = t2 >> 9;
        int cs = tile3 & 3, q = tile3 >> 2;
        int wv = q % 3, l = q / 3;
        int p = 16 * wv + (ln & 15);
        int n = 32 * cs + 8 * (ln >> 4) + j;
        float v = (p < 46) ? W3[l * 5888 + p * 128 + n] : 0.f;
        _Float16 a, b;
        split2h(v, a, b);
        W3F[(tile3 * 2 + 0) * 512 + ln * 8 + j] = a;
        W3F[(tile3 * 2 + 1) * 512 + ln * 8 + j] = b;
    } else if (id < 90624) {
        int t = id - 90112;
        int l = t >> 7, k = t & 127;
        float4 v;
        v.x = W1[l * 384 + k * 3 + 0];
        v.y = W1[l * 384 + k * 3 + 1];
        v.z = W1[l * 384 + k * 3 + 2];
        v.w = b1[l * 128 + k];
        w1p[t] = v;
    }
}

// v15: wave-autonomous. One 64-lane wave owns 32 samples end-to-end:
// no __syncthreads anywhere; in-wave LDS transposes ordered by WAVE_SYNC.
// B-fragments preloaded to registers once (16 x half8 = 64 VGPR), reused
// across all n-tiles -> 4x fewer ds_reads and safe plane overwrite after
// a single lgkmcnt drain. Math is bit-identical to v14 (same FMA order,
// same split4_pk, same MFMA accumulation order) -> absmax unchanged.
// LDS/wave 17024 B -> 9 independent waves/CU (uncorrelated stalls).
__global__ __launch_bounds__(64, 2)
void rqs_v15(const float* __restrict__ inp, const float* __restrict__ cond,
             const _Float16* __restrict__ W2F, const _Float16* __restrict__ W3F,
             const float4* __restrict__ w1p,
             const float* __restrict__ b2, const float* __restrict__ b3,
             float* __restrict__ out, int B)
{
    __shared__ __align__(16) _Float16 planes[2][32][128];   // 16384 B; pbuf overlays
    __shared__ float xbuf[32][5];

    char* plw = (char*)&planes[0][0][0];
    const char* pl = plw;

    const int ln   = threadIdx.x;              // 0..63
    const int base = blockIdx.x * 32;
    const int sm   = ln & 15;
    const int qd   = ln >> 4;                  // 0..3
    const int s1   = ln & 31;                  // sample slot
    const int hi   = ln >> 5;                  // k-half / f index

    // layer-invariant LDS addresses
    int rdaddr[2][4];                          // b-frag reads [st][cs]
    #pragma unroll
    for (int st = 0; st < 2; ++st)
        #pragma unroll
        for (int cs = 0; cs < 4; ++cs)
            rdaddr[st][cs] = (16 * st + sm) * 256 + (((4 * cs + qd) ^ sm) << 4);
    const int wrb = s1 * 256 + hi * 8;         // phase-1 write base (half4 slot)

    if (ln < 32) {
        float4 xi = reinterpret_cast<const float4*>(inp)[base + ln];
        xbuf[ln][0] = xi.x; xbuf[ln][1] = xi.y;
        xbuf[ln][2] = xi.z; xbuf[ln][3] = xi.w;
        xbuf[ln][4] = cond[base + ln];
    }
    float ladreg = 0.f;
    WAVE_SYNC();

    #pragma unroll 1
    for (int l = 0; l < 4; ++l) {
        int mi0, mi1, ii0, ii1;
        switch (l) {
            case 0:  mi0 = 0; mi1 = 2; ii0 = 1; ii1 = 3; break;
            case 1:  mi0 = 1; mi1 = 3; ii0 = 0; ii1 = 2; break;
            case 2:  mi0 = 0; mi1 = 1; ii0 = 2; ii1 = 3; break;
            default: mi0 = 2; mi1 = 3; ii0 = 0; ii1 = 1; break;
        }

        // ---- phase 1: h1 planes. lane (s1,hi): k = 8g + 4hi + j, g=0..15 ----
        {
            float m0 = xbuf[s1][mi0], m1 = xbuf[s1][mi1], cc = xbuf[s1][4];
            const float4* w1l = w1p + l * 128;
            #pragma unroll 4
            for (int g = 0; g < 16; ++g) {
                float v[4];
                #pragma unroll
                for (int j = 0; j < 4; ++j) {
                    float4 w4 = w1l[g * 8 + hi * 4 + j];
                    v[j] = fmaxf(fmaf(w4.x, m0, fmaf(w4.y, m1, fmaf(w4.z, cc, w4.w))), 0.f);
                }
                half4 p0, p1;
                split4_pk(v, p0, p1);
                char* wp = plw + wrb + ((g ^ sm) << 4);
                *(half4*)(wp)        = p0;
                *(half4*)(wp + 8192) = p1;
            }
        }
        WAVE_SYNC();   // h1 planes ready (wave-local)

        // ---- GEMM2: preload all h1 b-frags to regs, then 8 n-tiles ----
        half8 bf[2][4][2];
        #pragma unroll
        for (int st = 0; st < 2; ++st)
            #pragma unroll
            for (int cs = 0; cs < 4; ++cs) {
                bf[st][cs][0] = *(const half8*)(pl + rdaddr[st][cs]);
                bf[st][cs][1] = *(const half8*)(pl + rdaddr[st][cs] + 8192);
            }
        WAVE_SYNC();   // all h1 reads landed -> h2 overwrite of planes is safe

        const half8* W2F8 = (const half8*)W2F;
        #pragma unroll 1
        for (int np = 0; np < 4; ++np) {       // n-tile pairs: nt = 2np, 2np+1
            f32x4 accA[2][2], accB[2][2];      // [i][st]
            #pragma unroll
            for (int i = 0; i < 2; ++i) {
                float4 bias = *(const float4*)(b2 + l * 128 + (2 * np + i) * 16 + 4 * qd);
                #pragma unroll
                for (int st = 0; st < 2; ++st) {
                    accA[i][st] = (f32x4){bias.x, bias.y, bias.z, bias.w};
                    accB[i][st] = (f32x4){0.f, 0.f, 0.f, 0.f};
                }
            }
            #pragma unroll
            for (int cs = 0; cs < 4; ++cs) {
                #pragma unroll
                for (int i = 0; i < 2; ++i) {
                    int tile = l * 8 + 2 * np + i;
                    half8 A0 = W2F8[((tile * 4 + cs) * 2 + 0) * 64 + ln];
                    half8 A1 = W2F8[((tile * 4 + cs) * 2 + 1) * 64 + ln];
                    #pragma unroll
                    for (int st = 0; st < 2; ++st) {
                        accA[i][st] = MFMAH(A0, bf[st][cs][0], accA[i][st], 0, 0, 0);
                        accB[i][st] = MFMAH(A0, bf[st][cs][1], accB[i][st], 0, 0, 0);
                        accB[i][st] = MFMAH(A1, bf[st][cs][0], accB[i][st], 0, 0, 0);
                    }
                }
            }
            // h2 epilogue for these 2 n-tiles (reads done; planes writable)
            #pragma unroll
            for (int i = 0; i < 2; ++i) {
                int g = 2 * (2 * np + i) + (qd >> 1);
                #pragma unroll
                for (int st = 0; st < 2; ++st) {
                    float v[4];
                    #pragma unroll
                    for (int r = 0; r < 4; ++r)
                        v[r] = fmaxf(fmaf(INV2048, accB[i][st][r], accA[i][st][r]), 0.f);
                    half4 p0, p1;
                    split4_pk(v, p0, p1);
                    char* wp = plw + (16 * st + sm) * 256 + ((g ^ sm) << 4) + ((qd & 1) << 3);
                    *(half4*)(wp)        = p0;
                    *(half4*)(wp + 8192) = p1;
                }
            }
        }
        WAVE_SYNC();   // h2 planes ready

        // ---- GEMM3: preload h2 b-frags (reuse bf), then 3 p-tiles ----
        #pragma unroll
        for (int st = 0; st < 2; ++st)
            #pragma unroll
            for (int cs = 0; cs < 4; ++cs) {
                bf[st][cs][0] = *(const half8*)(pl + rdaddr[st][cs]);
                bf[st][cs][1] = *(const half8*)(pl + rdaddr[st][cs] + 8192);
            }
        WAVE_SYNC();   // all h2 reads landed -> pbuf overlay safe

        const half8* W3F8 = (const half8*)W3F;
        #pragma unroll 1
        for (int pt = 0; pt < 3; ++pt) {
            f32x4 a3A[2], a3B[2];
            #pragma unroll
            for (int st = 0; st < 2; ++st) {
                a3A[st] = (f32x4){0.f, 0.f, 0.f, 0.f};
                a3B[st] = (f32x4){0.f, 0.f, 0.f, 0.f};
            }
            #pragma unroll
            for (int cs = 0; cs < 4; ++cs) {
                int q = (l * 3 + pt) * 4 + cs;
                half8 A0 = W3F8[(q * 2 + 0) * 64 + ln];
                half8 A1 = W3F8[(q * 2 + 1) * 64 + ln];
                #pragma unroll
                for (int st = 0; st < 2; ++st) {
                    a3A[st] = MFMAH(A0, bf[st][cs][0], a3A[st], 0, 0, 0);
                    a3B[st] = MFMAH(A0, bf[st][cs][1], a3B[st], 0, 0, 0);
                    a3B[st] = MFMAH(A1, bf[st][cs][0], a3B[st], 0, 0, 0);
                }
            }
            #pragma unroll
            for (int st = 0; st < 2; ++st) {
                float4 pv;
                pv.x = fmaf(INV2048, a3B[st][0], a3A[st][0]);
                pv.y = fmaf(INV2048, a3B[st][1], a3A[st][1]);
                pv.z = fmaf(INV2048, a3B[st][2], a3A[st][2]);
                pv.w = fmaf(INV2048, a3B[st][3], a3A[st][3]);
                *(float4*)(plw + (16 * st + sm) * 208 + (16 * pt + 4 * qd) * 4) = pv;
            }
        }
        WAVE_SYNC();   // params visible

        // ---- spline: all 64 lanes, one spline each: f = hi, s = s1 ----
        {
            const float* b3l = b3 + l * 46;
            const float4* prow = (const float4*)(pl + s1 * 208);
            float pr[23];
            #pragma unroll
            for (int i = 0; i < 12; ++i) {
                float4 q = prow[i];
                pr[2 * i] = (hi ? q.y : q.x) + b3l[4 * i + hi];
                if (2 * i + 1 < 23)
                    pr[2 * i + 1] = (hi ? q.w : q.z) + b3l[4 * i + 2 + hi];
            }

            float xin = xbuf[s1][hi == 0 ? ii0 : ii1];

            float d[9];
            d[0] = 1.f; d[8] = 1.f;
            #pragma unroll
            for (int k = 1; k < 8; ++k) d[k] = 1e-6f + softplus_f(pr[16 + k - 1]);

            bool inside = (xin >= -TAILB) && (xin <= TAILB);
            float xc = fminf(fmaxf(xin, -TAILB), TAILB);

            float mw = pr[0], mh = pr[8];
            #pragma unroll
            for (int k = 1; k < 8; ++k) { mw = fmaxf(mw, pr[k]); mh = fmaxf(mh, pr[8 + k]); }
            float ew[8], eh[8], swm = 0.f, shm = 0.f;
            #pragma unroll
            for (int k = 0; k < 8; ++k) {
                ew[k] = __expf(pr[k] - mw);     swm += ew[k];
                eh[k] = __expf(pr[8 + k] - mh); shm += eh[k];
            }
            const float c1 = 1.f - 8e-6f;
            float isw = __fdividef(c1, swm), ish = __fdividef(c1, shm);

            float cum_w = 0.f, cum_h = 0.f;
            float cwk = -TAILB, chk = -TAILB;
            float s_cw = -TAILB, s_w = 2.f * TAILB, s_ch = -TAILB, s_h = 2.f * TAILB;
            float s_d0 = 1.f, s_d1 = d[1];
            #pragma unroll
            for (int k = 0; k < 8; ++k) {
                cum_w += fmaf(ew[k], isw, 1e-6f);
                cum_h += fmaf(eh[k], ish, 1e-6f);
                float cwn = (k == 7) ? TAILB : fmaf(2.f * TAILB, cum_w, -TAILB);
                float chn = (k == 7) ? TAILB : fmaf(2.f * TAILB, cum_h, -TAILB);
                bool ge = (xc >= cwk);
                s_cw = ge ? cwk : s_cw;  s_w = ge ? (cwn - cwk) : s_w;
                s_ch = ge ? chk : s_ch;  s_h = ge ? (chn - chk) : s_h;
                s_d0 = ge ? d[k] : s_d0; s_d1 = ge ? d[k + 1] : s_d1;
                cwk = cwn; chk = chn;
            }

            float rw    = __fdividef(1.f, s_w);
            float th    = (xc - s_cw) * rw;
            float delta = s_h * rw;
            float omt   = 1.f - th;
            float tomt  = th * omt;
            float num   = s_h * fmaf(delta, th * th, s_d0 * tomt);
            float den   = fmaf(s_d0 + s_d1 - 2.f * delta, tomt, delta);
            float y     = s_ch + __fdividef(num, den);
            float dnum  = delta * delta * (s_d1 * th * th + 2.f * delta * tomt + s_d0 * omt * omt);
            float lad   = __logf(dnum) - 2.f * __logf(den);

            xbuf[s1][hi == 0 ? ii0 : ii1] = inside ? y : xin;
            ladreg += inside ? lad : 0.f;
        }
        WAVE_SYNC();   // x updated + pbuf reads drained; next phase-1 may overwrite
    } // l

    float lsum = ladreg + __shfl(ladreg, (ln + 32) & 63, 64);
    if (ln < 32) {
        float4 xo;
        xo.x = xbuf[ln][0]; xo.y = xbuf[ln][1];
        xo.z = xbuf[ln][2]; xo.w = xbuf[ln][3];
        reinterpret_cast<float4*>(out)[base + ln] = xo;
        out[(size_t)B * 4 + base + ln] = lsum;
    }
}

extern "C" void kernel_launch(void* const* d_in, const int* in_sizes, int n_in,
                              void* d_out, int out_size, void* d_ws, size_t ws_size,
                              hipStream_t stream) {
    const float* inp  = (const float*)d_in[0];
    const float* cond = (const float*)d_in[1];
    const float* W1   = (const float*)d_in[2];
    const float* b1   = (const float*)d_in[3];
    const float* W2   = (const float*)d_in[4];
    const float* b2   = (const float*)d_in[5];
    const float* W3   = (const float*)d_in[6];
    const float* b3   = (const float*)d_in[7];
    float* out = (float*)d_out;
    int B = in_sizes[0] / 4;

    char* ws = (char*)d_ws;
    _Float16* W2F = (_Float16*)(ws);            // 262144 B
    _Float16* W3F = (_Float16*)(ws + 262144);   // 98304 B
    float4*   w1p = (float4*)(ws + 360448);     // 8192 B

    hipLaunchKernelGGL(prep_v15, dim3(354), dim3(256), 0, stream,
                       W1, b1, W2, W3, W2F, W3F, w1p);
    hipLaunchKernelGGL(rqs_v15, dim3(B / 32), dim3(64), 0, stream,
                       inp, cond, W2F, W3F, w1p, b2, b3, out, B);
}

// Round 2
// 252.067 us; speedup vs baseline: 1.0840x; 1.0691x over previous
//
#include <hip/hip_runtime.h>

#define TAILB 12.0f
#define INV2048 4.8828125e-4f

typedef _Float16 half8 __attribute__((ext_vector_type(8)));
typedef _Float16 half4 __attribute__((ext_vector_type(4)));
typedef __fp16 fp16x2 __attribute__((ext_vector_type(2)));   // pkrtz return type
typedef __attribute__((ext_vector_type(4))) float f32x4;

#define MFMAH __builtin_amdgcn_mfma_f32_16x16x32_f16

// In-wave LDS ordering fence (lockstep wave64): replaces __syncthreads for
// wave-local producer->consumer through LDS. sched_barrier pins compiler
// scheduling (hipcc hoists reg-only MFMA past inline-asm waitcnt otherwise).
#define WAVE_SYNC() do {                                  \
    __builtin_amdgcn_sched_barrier(0);                    \
    asm volatile("s_waitcnt lgkmcnt(0)" ::: "memory");    \
    __builtin_amdgcn_sched_barrier(0);                    \
} while (0)

// fast softplus: log(1+e^z); abs err ~2^-24
__device__ __forceinline__ float softplus_f(float z) {
    return (z > 15.f) ? z : __logf(1.f + __expf(z));
}

// fp16 2-term scaled split (RNE, prep only)
__device__ __forceinline__ void split2h(float v, _Float16& o0, _Float16& o1) {
    _Float16 h0 = (_Float16)v;
    float r1 = v - (float)h0;
    o0 = h0;
    o1 = (_Float16)(r1 * 2048.0f);
}

// pkrtz-based split of 4 values -> two packed half4 planes (RTZ both terms)
__device__ __forceinline__ void split4_pk(const float* v, half4& p0, half4& p1) {
    fp16x2 lo = __builtin_amdgcn_cvt_pkrtz(v[0], v[1]);
    fp16x2 hi = __builtin_amdgcn_cvt_pkrtz(v[2], v[3]);
    float r0 = (v[0] - (float)lo.x) * 2048.f;
    float r1 = (v[1] - (float)lo.y) * 2048.f;
    float r2 = (v[2] - (float)hi.x) * 2048.f;
    float r3 = (v[3] - (float)hi.y) * 2048.f;
    fp16x2 rlo = __builtin_amdgcn_cvt_pkrtz(r0, r1);
    fp16x2 rhi = __builtin_amdgcn_cvt_pkrtz(r2, r3);
    p0 = (half4){(_Float16)lo.x, (_Float16)lo.y, (_Float16)hi.x, (_Float16)hi.y};
    p1 = (half4){(_Float16)rlo.x, (_Float16)rlo.y, (_Float16)rhi.x, (_Float16)rhi.y};
}

// ---------------- prep: identical layout to v10..v15 ----------------
__global__ __launch_bounds__(256)
void prep_v16(const float* __restrict__ W1, const float* __restrict__ b1,
              const float* __restrict__ W2, const float* __restrict__ W3,
              _Float16* __restrict__ W2F, _Float16* __restrict__ W3F,
              float4* __restrict__ w1p)
{
    int id = blockIdx.x * 256 + threadIdx.x;
    if (id < 65536) {
        int j = id & 7, ln = (id >> 3) & 63, tile = id >> 9;
        int cs = tile & 3, t = (tile >> 2) & 1, wv = (tile >> 3) & 3, l = tile >> 5;
        int n = 32 * wv + 16 * t + (ln & 15);
        int k = 32 * cs + 8 * (ln >> 4) + j;
        _Float16 a, b;
        split2h(W2[l * 16384 + n * 128 + k], a, b);
        W2F[(tile * 2 + 0) * 512 + ln * 8 + j] = a;
        W2F[(tile * 2 + 1) * 512 + ln * 8 + j] = b;
    } else if (id < 90112) {
        int t2 = id - 65536;
        int j = t2 & 7, ln = (t2 >> 3) & 63, tile3 = t2 >> 9;
        int cs = tile3 & 3, q = tile3 >> 2;
        int wv = q % 3, l = q / 3;
        int p = 16 * wv + (ln & 15);
        int n = 32 * cs + 8 * (ln >> 4) + j;
        float v = (p < 46) ? W3[l * 5888 + p * 128 + n] : 0.f;
        _Float16 a, b;
        split2h(v, a, b);
        W3F[(tile3 * 2 + 0) * 512 + ln * 8 + j] = a;
        W3F[(tile3 * 2 + 1) * 512 + ln * 8 + j] = b;
    } else if (id < 90624) {
        int t = id - 90112;
        int l = t >> 7, k = t & 127;
        float4 v;
        v.x = W1[l * 384 + k * 3 + 0];
        v.y = W1[l * 384 + k * 3 + 1];
        v.z = W1[l * 384 + k * 3 + 2];
        v.w = b1[l * 128 + k];
        w1p[t] = v;
    }
}

// v16: wave-autonomous (v15) + chunked transpose through an 8 KB LDS buffer.
// LDS is only a transpose medium (the wave holds the full plane content in
// 64 VGPR of b-frags), so: phase-1 produces k-half [0,64) for all 32 samples,
// preload those b-frags, overwrite with k-half [64,128), preload rest. Same
// for h2 chunked by n-half between GEMM2 n-tile groups. pbuf overlays the
// buffer. LDS 17408 -> 8832 B; __launch_bounds__(64,3) -> ~12 waves/CU.
// A-tiles still loaded once per wave. Math bit-identical to v15 (same
// FMA/relu/split/MFMA-order per value) -> absmax unchanged.
__global__ __launch_bounds__(64, 3)
void rqs_v16(const float* __restrict__ inp, const float* __restrict__ cond,
             const _Float16* __restrict__ W2F, const _Float16* __restrict__ W3F,
             const float4* __restrict__ w1p,
             const float* __restrict__ b2, const float* __restrict__ b3,
             float* __restrict__ out, int B)
{
    __shared__ __align__(16) char P[8192];     // planeA [32][128B] + planeB @4096; pbuf overlays
    __shared__ float xbuf[32][5];

    char* plw = P;
    const char* pl = P;

    const int ln   = threadIdx.x;              // 0..63
    const int base = blockIdx.x * 32;
    const int sm   = ln & 15;
    const int qd   = ln >> 4;                  // 0..3
    const int s1   = ln & 31;                  // sample slot
    const int hi   = ln >> 5;                  // half index

    // layer-invariant b-frag read addresses: row = 16st+sm, slot = (4csl+qd)^(row&7)
    int rdK[2][2];
    #pragma unroll
    for (int st = 0; st < 2; ++st)
        #pragma unroll
        for (int csl = 0; csl < 2; ++csl) {
            int row = 16 * st + sm;
            rdK[st][csl] = row * 128 + (((4 * csl + qd) ^ (row & 7)) << 4);
        }

    if (ln < 32) {
        float4 xi = reinterpret_cast<const float4*>(inp)[base + ln];
        xbuf[ln][0] = xi.x; xbuf[ln][1] = xi.y;
        xbuf[ln][2] = xi.z; xbuf[ln][3] = xi.w;
        xbuf[ln][4] = cond[base + ln];
    }
    float ladreg = 0.f;
    WAVE_SYNC();

    #pragma unroll 1
    for (int l = 0; l < 4; ++l) {
        int mi0, mi1, ii0, ii1;
        switch (l) {
            case 0:  mi0 = 0; mi1 = 2; ii0 = 1; ii1 = 3; break;
            case 1:  mi0 = 1; mi1 = 3; ii0 = 0; ii1 = 2; break;
            case 2:  mi0 = 0; mi1 = 1; ii0 = 2; ii1 = 3; break;
            default: mi0 = 2; mi1 = 3; ii0 = 0; ii1 = 1; break;
        }

        // ---- phase 1 + transpose, chunked by k-half through the 8KB buffer ----
        half8 bf[2][4][2];                     // [st][cs][plane] -- full h1 in regs
        {
            float m0 = xbuf[s1][mi0], m1 = xbuf[s1][mi1], cc = xbuf[s1][4];
            const float4* w1l = w1p + l * 128;
            #pragma unroll
            for (int kh = 0; kh < 2; ++kh) {
                // lane (s1,hi) computes k in [64kh+32hi, +32): groups gl=4hi+j4
                #pragma unroll
                for (int j4 = 0; j4 < 4; ++j4) {
                    int gl = 4 * hi + j4;
                    int g  = 8 * kh + gl;      // global k-group; W1 rows 8g..8g+7
                    float v[8];
                    #pragma unroll
                    for (int r = 0; r < 8; ++r) {
                        float4 w4 = w1l[g * 8 + r];
                        v[r] = fmaxf(fmaf(w4.x, m0, fmaf(w4.y, m1, fmaf(w4.z, cc, w4.w))), 0.f);
                    }
                    half4 a0, a1, b0h, b1h;
                    split4_pk(v, a0, a1);
                    split4_pk(v + 4, b0h, b1h);
                    half8 p0 = {a0.x, a0.y, a0.z, a0.w, b0h.x, b0h.y, b0h.z, b0h.w};
                    half8 p1 = {a1.x, a1.y, a1.z, a1.w, b1h.x, b1h.y, b1h.z, b1h.w};
                    char* wp = plw + s1 * 128 + ((gl ^ (s1 & 7)) << 4);
                    *(half8*)(wp)        = p0;
                    *(half8*)(wp + 4096) = p1;
                }
                WAVE_SYNC();   // k-half planes ready
                #pragma unroll
                for (int st = 0; st < 2; ++st)
                    #pragma unroll
                    for (int csl = 0; csl < 2; ++csl) {
                        bf[st][2 * kh + csl][0] = *(const half8*)(pl + rdK[st][csl]);
                        bf[st][2 * kh + csl][1] = *(const half8*)(pl + rdK[st][csl] + 4096);
                    }
                WAVE_SYNC();   // reads landed -> buffer reusable
            }
        }

        // ---- GEMM2: single A pass; h2 chunked by n-half into the buffer ----
        half8 bf3[2][4][2];                    // [st][cs][plane] -- full h2 in regs
        const half8* W2F8 = (const half8*)W2F;
        #pragma unroll
        for (int ntg = 0; ntg < 2; ++ntg) {
            #pragma unroll 1
            for (int ntl = 0; ntl < 4; ++ntl) {
                int nt = 4 * ntg + ntl;        // n-tile 0..7
                f32x4 accA[2], accB[2];        // [st]
                float4 bias = *(const float4*)(b2 + l * 128 + nt * 16 + 4 * qd);
                #pragma unroll
                for (int st = 0; st < 2; ++st) {
                    accA[st] = (f32x4){bias.x, bias.y, bias.z, bias.w};
                    accB[st] = (f32x4){0.f, 0.f, 0.f, 0.f};
                }
                #pragma unroll
                for (int cs = 0; cs < 4; ++cs) {
                    int tile = l * 8 + nt;
                    half8 A0 = W2F8[((tile * 4 + cs) * 2 + 0) * 64 + ln];
                    half8 A1 = W2F8[((tile * 4 + cs) * 2 + 1) * 64 + ln];
                    #pragma unroll
                    for (int st = 0; st < 2; ++st) {
                        accA[st] = MFMAH(A0, bf[st][cs][0], accA[st], 0, 0, 0);
                        accB[st] = MFMAH(A0, bf[st][cs][1], accB[st], 0, 0, 0);
                        accB[st] = MFMAH(A1, bf[st][cs][0], accB[st], 0, 0, 0);
                    }
                }
                // h2 epilogue: n rows 16nt+4qd+r for samples (st,sm)
                #pragma unroll
                for (int st = 0; st < 2; ++st) {
                    float v[4];
                    #pragma unroll
                    for (int r = 0; r < 4; ++r)
                        v[r] = fmaxf(fmaf(INV2048, accB[st][r], accA[st][r]), 0.f);
                    half4 p0, p1;
                    split4_pk(v, p0, p1);
                    int row = 16 * st + sm;
                    int gl  = 2 * ntl + (qd >> 1);   // local n-group in [0,8)
                    char* wp = plw + row * 128 + ((gl ^ (row & 7)) << 4) + ((qd & 1) << 3);
                    *(half4*)(wp)        = p0;
                    *(half4*)(wp + 4096) = p1;
                }
            }
            WAVE_SYNC();   // h2 n-half ready
            #pragma unroll
            for (int st = 0; st < 2; ++st)
                #pragma unroll
                for (int csl = 0; csl < 2; ++csl) {
                    bf3[st][2 * ntg + csl][0] = *(const half8*)(pl + rdK[st][csl]);
                    bf3[st][2 * ntg + csl][1] = *(const half8*)(pl + rdK[st][csl] + 4096);
                }
            WAVE_SYNC();   // reads landed -> buffer reusable
        }

        // ---- GEMM3: all from regs; pv writes overlay the buffer (pbuf) ----
        const half8* W3F8 = (const half8*)W3F;
        #pragma unroll 1
        for (int pt = 0; pt < 3; ++pt) {
            f32x4 a3A[2], a3B[2];
            #pragma unroll
            for (int st = 0; st < 2; ++st) {
                a3A[st] = (f32x4){0.f, 0.f, 0.f, 0.f};
                a3B[st] = (f32x4){0.f, 0.f, 0.f, 0.f};
            }
            #pragma unroll
            for (int cs = 0; cs < 4; ++cs) {
                int q = (l * 3 + pt) * 4 + cs;
                half8 A0 = W3F8[(q * 2 + 0) * 64 + ln];
                half8 A1 = W3F8[(q * 2 + 1) * 64 + ln];
                #pragma unroll
                for (int st = 0; st < 2; ++st) {
                    a3A[st] = MFMAH(A0, bf3[st][cs][0], a3A[st], 0, 0, 0);
                    a3B[st] = MFMAH(A0, bf3[st][cs][1], a3B[st], 0, 0, 0);
                    a3B[st] = MFMAH(A1, bf3[st][cs][0], a3B[st], 0, 0, 0);
                }
            }
            #pragma unroll
            for (int st = 0; st < 2; ++st) {
                float4 pv;
                pv.x = fmaf(INV2048, a3B[st][0], a3A[st][0]);
                pv.y = fmaf(INV2048, a3B[st][1], a3A[st][1]);
                pv.z = fmaf(INV2048, a3B[st][2], a3A[st][2]);
                pv.w = fmaf(INV2048, a3B[st][3], a3A[st][3]);
                *(float4*)(plw + (16 * st + sm) * 208 + (16 * pt + 4 * qd) * 4) = pv;
            }
        }
        WAVE_SYNC();   // params visible

        // ---- spline: all 64 lanes, one spline each: f = hi, s = s1 ----
        {
            const float* b3l = b3 + l * 46;
            const float4* prow = (const float4*)(pl + s1 * 208);
            float pr[23];
            #pragma unroll
            for (int i = 0; i < 12; ++i) {
                float4 q = prow[i];
                pr[2 * i] = (hi ? q.y : q.x) + b3l[4 * i + hi];
                if (2 * i + 1 < 23)
                    pr[2 * i + 1] = (hi ? q.w : q.z) + b3l[4 * i + 2 + hi];
            }

            float xin = xbuf[s1][hi == 0 ? ii0 : ii1];

            float d[9];
            d[0] = 1.f; d[8] = 1.f;
            #pragma unroll
            for (int k = 1; k < 8; ++k) d[k] = 1e-6f + softplus_f(pr[16 + k - 1]);

            bool inside = (xin >= -TAILB) && (xin <= TAILB);
            float xc = fminf(fmaxf(xin, -TAILB), TAILB);

            float mw = pr[0], mh = pr[8];
            #pragma unroll
            for (int k = 1; k < 8; ++k) { mw = fmaxf(mw, pr[k]); mh = fmaxf(mh, pr[8 + k]); }
            float ew[8], eh[8], swm = 0.f, shm = 0.f;
            #pragma unroll
            for (int k = 0; k < 8; ++k) {
                ew[k] = __expf(pr[k] - mw);     swm += ew[k];
                eh[k] = __expf(pr[8 + k] - mh); shm += eh[k];
            }
            const float c1 = 1.f - 8e-6f;
            float isw = __fdividef(c1, swm), ish = __fdividef(c1, shm);

            float cum_w = 0.f, cum_h = 0.f;
            float cwk = -TAILB, chk = -TAILB;
            float s_cw = -TAILB, s_w = 2.f * TAILB, s_ch = -TAILB, s_h = 2.f * TAILB;
            float s_d0 = 1.f, s_d1 = d[1];
            #pragma unroll
            for (int k = 0; k < 8; ++k) {
                cum_w += fmaf(ew[k], isw, 1e-6f);
                cum_h += fmaf(eh[k], ish, 1e-6f);
                float cwn = (k == 7) ? TAILB : fmaf(2.f * TAILB, cum_w, -TAILB);
                float chn = (k == 7) ? TAILB : fmaf(2.f * TAILB, cum_h, -TAILB);
                bool ge = (xc >= cwk);
                s_cw = ge ? cwk : s_cw;  s_w = ge ? (cwn - cwk) : s_w;
                s_ch = ge ? chk : s_ch;  s_h = ge ? (chn - chk) : s_h;
                s_d0 = ge ? d[k] : s_d0; s_d1 = ge ? d[k + 1] : s_d1;
                cwk = cwn; chk = chn;
            }

            float rw    = __fdividef(1.f, s_w);
            float th    = (xc - s_cw) * rw;
            float delta = s_h * rw;
            float omt   = 1.f - th;
            float tomt  = th * omt;
            float num   = s_h * fmaf(delta, th * th, s_d0 * tomt);
            float den   = fmaf(s_d0 + s_d1 - 2.f * delta, tomt, delta);
            float y     = s_ch + __fdividef(num, den);
            float dnum  = delta * delta * (s_d1 * th * th + 2.f * delta * tomt + s_d0 * omt * omt);
            float lad   = __logf(dnum) - 2.f * __logf(den);

            xbuf[s1][hi == 0 ? ii0 : ii1] = inside ? y : xin;
            ladreg += inside ? lad : 0.f;
        }
        WAVE_SYNC();   // x updated + pbuf reads drained; next phase-1 may overwrite
    } // l

    float lsum = ladreg + __shfl(ladreg, (ln + 32) & 63, 64);
    if (ln < 32) {
        float4 xo;
        xo.x = xbuf[ln][0]; xo.y = xbuf[ln][1];
        xo.z = xbuf[ln][2]; xo.w = xbuf[ln][3];
        reinterpret_cast<float4*>(out)[base + ln] = xo;
        out[(size_t)B * 4 + base + ln] = lsum;
    }
}

extern "C" void kernel_launch(void* const* d_in, const int* in_sizes, int n_in,
                              void* d_out, int out_size, void* d_ws, size_t ws_size,
                              hipStream_t stream) {
    const float* inp  = (const float*)d_in[0];
    const float* cond = (const float*)d_in[1];
    const float* W1   = (const float*)d_in[2];
    const float* b1   = (const float*)d_in[3];
    const float* W2   = (const float*)d_in[4];
    const float* b2   = (const float*)d_in[5];
    const float* W3   = (const float*)d_in[6];
    const float* b3   = (const float*)d_in[7];
    float* out = (float*)d_out;
    int B = in_sizes[0] / 4;

    char* ws = (char*)d_ws;
    _Float16* W2F = (_Float16*)(ws);            // 262144 B
    _Float16* W3F = (_Float16*)(ws + 262144);   // 98304 B
    float4*   w1p = (float4*)(ws + 360448);     // 8192 B

    hipLaunchKernelGGL(prep_v16, dim3(354), dim3(256), 0, stream,
                       W1, b1, W2, W3, W2F, W3F, w1p);
    hipLaunchKernelGGL(rqs_v16, dim3(B / 32), dim3(64), 0, stream,
                       inp, cond, W2F, W3F, w1p, b2, b3, out, B);
}